// Round 6
// baseline (210.223 us; speedup 1.0000x reference)
//
#include <hip/hip_runtime.h>
#include <math.h>

#define HID 128
#define NHEAD 8
#define NL 3
#define NS 256
#define ROWS 4096

typedef __attribute__((ext_vector_type(8))) short bf16x8;
typedef __attribute__((ext_vector_type(4))) float f32x4;

__device__ __forceinline__ float us2f(unsigned short s) { return __uint_as_float(((unsigned)s) << 16); }
__device__ __forceinline__ unsigned short f2b(float f) {   // RNE fp32->bf16
    unsigned u = __float_as_uint(f);
    return (unsigned short)((u + 0x7fff + ((u >> 16) & 1)) >> 16);
}

// ---------- prep: weight split+transpose to bf16 hi/lo planes [N][K] + edge scalars + embed
// blocks: [0,144) Wh, [144,336) W1, [336,528) W2, 528 edge scalars, [529,1041) embed h=nf@Wn
__global__ __launch_bounds__(256) void k_prep(
    const float* __restrict__ Wh, const float* __restrict__ W1, const float* __restrict__ W2,
    const float* __restrict__ We_in, const float* __restrict__ We,
    const float* __restrict__ nf, const float* __restrict__ Wn,
    unsigned short* __restrict__ WhH, unsigned short* __restrict__ WhL,
    unsigned short* __restrict__ W1H, unsigned short* __restrict__ W1L,
    unsigned short* __restrict__ W2H, unsigned short* __restrict__ W2L,
    float* __restrict__ sbuf, float* __restrict__ h)
{
    int b = blockIdx.x, t = threadIdx.x;
    if (b >= 529) {                       // embed, vectorized: one float4 per thread
        int idx4 = (b - 529) * 256 + t;
        int r = idx4 >> 5, c4 = (idx4 & 31) * 4;
        float n0 = nf[2 * r], n1 = nf[2 * r + 1];
        float4 w0 = *(const float4*)&Wn[c4];
        float4 w1 = *(const float4*)&Wn[HID + c4];
        float4 o = {n0 * w0.x + n1 * w1.x, n0 * w0.y + n1 * w1.y,
                    n0 * w0.z + n1 * w1.z, n0 * w0.w + n1 * w1.w};
        *(float4*)&h[idx4 * 4] = o;
        return;
    }
    if (b == 528) {                       // edge scalars (rank-1 collapse of e @ We)
        if (t < NL * 2 * NHEAD) {
            int l = t / (2 * NHEAD), j = t % (2 * NHEAD);
            float acc = 0.f;
            for (int c = 0; c < HID; ++c)
                acc += We_in[c] * We[(long)(l * HID + c) * (2 * NHEAD) + j];
            sbuf[t] = acc;
        }
        return;
    }
    const float* S; unsigned short *OH, *OL; int K, N, kt, nt;
    if (b < 144) {
        int l = b / 48, rem = b % 48; kt = rem & 3; nt = rem >> 2; K = 128; N = 384;
        S = Wh + (long)l * 128 * 384; OH = WhH + (long)l * 384 * 128; OL = WhL + (long)l * 384 * 128;
    } else if (b < 336) {
        int b2 = b - 144; int l = b2 / 64, rem = b2 % 64; kt = rem & 3; nt = rem >> 2; K = 128; N = 512;
        S = W1 + (long)l * 128 * 512; OH = W1H + (long)l * 512 * 128; OL = W1L + (long)l * 512 * 128;
    } else {
        int b2 = b - 336; int l = b2 / 64, rem = b2 % 64; kt = rem & 15; nt = rem >> 4; K = 512; N = 128;
        S = W2 + (long)l * 512 * 128; OH = W2H + (long)l * 128 * 512; OL = W2L + (long)l * 128 * 512;
    }
    __shared__ float sm[32][33];
    int i0 = t >> 5, j = t & 31;
#pragma unroll
    for (int p = 0; p < 4; ++p) {
        int i = i0 + p * 8;
        sm[i][j] = S[(long)(kt * 32 + i) * N + nt * 32 + j];
    }
    __syncthreads();
#pragma unroll
    for (int p = 0; p < 4; ++p) {
        int n = i0 + p * 8;
        float v = sm[j][n];
        unsigned short hh = f2b(v);
        long o = (long)(nt * 32 + n) * K + kt * 32 + j;
        OH[o] = hh; OL[o] = f2b(v - us2f(hh));
    }
}

// ---------- fused LN + split-bf16 MFMA GEMM, K=128 single-shot, 64x64 tile, 4 waves.
// QKV producer. Output written TRANSPOSED: C^T[col][ROWS] — acc r=0..3 are consecutive
// rows of one col, so the transposed store packs into uint2 (8B) per plane.
__global__ __launch_bounds__(256) void k_fgemm(
    const float* __restrict__ x, const float* __restrict__ x2,
    const float* __restrict__ g, const float* __restrict__ b,
    const unsigned short* __restrict__ WH, const unsigned short* __restrict__ WL,
    unsigned short* __restrict__ Ch, unsigned short* __restrict__ Cl,
    int mode)
{
    __shared__ unsigned short sAh[64 * 136], sAl[64 * 136];   // [m][k]
    __shared__ unsigned short sWh[64 * 136], sWl[64 * 136];   // [n][k]
    int t = threadIdx.x;
    int row0 = blockIdx.y * 64, col0 = blockIdx.x * 64;

#pragma unroll
    for (int p = 0; p < 4; ++p) {
        int rr = (t >> 4) + p * 16, ck = t & 15;
        *(uint4*)&sWh[rr * 136 + ck * 8] = *(const uint4*)&WH[(long)(col0 + rr) * 128 + ck * 8];
        *(uint4*)&sWl[rr * 136 + ck * 8] = *(const uint4*)&WL[(long)(col0 + rr) * 128 + ck * 8];
    }
#pragma unroll
    for (int pass = 0; pass < 2; ++pass) {
        int row = pass * 32 + (t >> 3);
        int p = t & 7, cb = p * 16;
        float v[16];
        const float* xp = x + (long)(row0 + row) * HID + cb;
#pragma unroll
        for (int j = 0; j < 16; j += 4) *(float4*)&v[j] = *(const float4*)(xp + j);
        if (x2) {
            const float* yp = x2 + (long)(row0 + row) * HID + cb;
#pragma unroll
            for (int j = 0; j < 16; j += 4) {
                float4 r4 = *(const float4*)(yp + j);
                v[j] += r4.x; v[j+1] += r4.y; v[j+2] += r4.z; v[j+3] += r4.w;
            }
        }
        float s = 0.f, s2 = 0.f;
#pragma unroll
        for (int j = 0; j < 16; ++j) { s += v[j]; s2 += v[j] * v[j]; }
        s  += __shfl_xor(s, 1);  s  += __shfl_xor(s, 2);  s  += __shfl_xor(s, 4);
        s2 += __shfl_xor(s2, 1); s2 += __shfl_xor(s2, 2); s2 += __shfl_xor(s2, 4);
        float mu  = s * (1.f / HID);
        float var = s2 * (1.f / HID) - mu * mu;
        float inv = rsqrtf(var + 1e-5f);
        unsigned short hi[16], lo[16];
#pragma unroll
        for (int j = 0; j < 16; ++j) {
            int c = cb + j;
            float o = (v[j] - mu) * inv * g[c] + b[c];
            hi[j] = f2b(o); lo[j] = f2b(o - us2f(hi[j]));
        }
        *(uint4*)&sAh[row * 136 + cb]     = *(uint4*)&hi[0];
        *(uint4*)&sAh[row * 136 + cb + 8] = *(uint4*)&hi[8];
        *(uint4*)&sAl[row * 136 + cb]     = *(uint4*)&lo[0];
        *(uint4*)&sAl[row * 136 + cb + 8] = *(uint4*)&lo[8];
    }
    __syncthreads();

    int w = t >> 6, lane = t & 63;
    int m = lane & 15, quad = lane >> 4;
    f32x4 acc[4];
#pragma unroll
    for (int i = 0; i < 4; ++i) acc[i] = (f32x4){0.f, 0.f, 0.f, 0.f};
#pragma unroll
    for (int c = 0; c < 4; ++c) {
        bf16x8 ah = *(const bf16x8*)&sAh[(w * 16 + m) * 136 + c * 32 + quad * 8];
        bf16x8 al = *(const bf16x8*)&sAl[(w * 16 + m) * 136 + c * 32 + quad * 8];
#pragma unroll
        for (int nt = 0; nt < 4; ++nt) {
            bf16x8 wh = *(const bf16x8*)&sWh[(nt * 16 + m) * 136 + c * 32 + quad * 8];
            bf16x8 wl = *(const bf16x8*)&sWl[(nt * 16 + m) * 136 + c * 32 + quad * 8];
            acc[nt] = __builtin_amdgcn_mfma_f32_16x16x32_bf16(ah, wh, acc[nt], 0, 0, 0);
            acc[nt] = __builtin_amdgcn_mfma_f32_16x16x32_bf16(ah, wl, acc[nt], 0, 0, 0);
            acc[nt] = __builtin_amdgcn_mfma_f32_16x16x32_bf16(al, wh, acc[nt], 0, 0, 0);
        }
    }
    // transposed epilogue: lane holds rows quad*4..+3 of col nt*16+m -> packed uint2
#pragma unroll
    for (int nt = 0; nt < 4; ++nt) {
        unsigned short hi4[4], lo4[4];
#pragma unroll
        for (int r = 0; r < 4; ++r) {
            float v = acc[nt][r];
            if (mode) v = fmaxf(v, 0.f);
            hi4[r] = f2b(v); lo4[r] = f2b(v - us2f(hi4[r]));
        }
        long o = (long)(col0 + nt * 16 + m) * ROWS + row0 + w * 16 + quad * 4;
        *(uint2*)&Ch[o] = *(const uint2*)hi4;
        *(uint2*)&Cl[o] = *(const uint2*)lo4;
    }
}

// ---------- fused MLP: LN2(y+h) -> W1 GEMM + relu -> W2 GEMM + residual (+decode).
// 512 threads / 8 waves (2 waves/SIMD); 16 rows/block, 256 blocks.
__global__ __launch_bounds__(512, 1) void k_mlp(
    const float* __restrict__ y, const float* __restrict__ h,
    const float* __restrict__ g, const float* __restrict__ b,
    const unsigned short* __restrict__ W1H_, const unsigned short* __restrict__ W1L_,
    const unsigned short* __restrict__ W2H_, const unsigned short* __restrict__ W2L_,
    float* __restrict__ hout, const float* __restrict__ Wdec, float* __restrict__ out)
{
    __shared__ __align__(16) unsigned short sAh[16 * 136], sAl[16 * 136];   // LN2 out planes [row][k]
    __shared__ __align__(16) unsigned short sHh[16 * 520], sHl[16 * 520];   // hid planes [row][k], k=512
    int t = threadIdx.x;
    int row0 = blockIdx.x * 16;
    int w = t >> 6, lane = t & 63;
    int m = lane & 15, quad = lane >> 4;

    // W1 fragment base for this wave's k-slab; prefetch c=0 fragments above the barrier
    const unsigned short* w1h = W1H_ + (long)(w * 64 + m) * 128 + quad * 8;
    const unsigned short* w1l = W1L_ + (long)(w * 64 + m) * 128 + quad * 8;
    bf16x8 p1h[4], p1l[4];
#pragma unroll
    for (int nt = 0; nt < 4; ++nt) {
        p1h[nt] = *(const bf16x8*)&w1h[nt * 16 * 128];
        p1l[nt] = *(const bf16x8*)&w1l[nt * 16 * 128];
    }

    // ---- LN2(y + h): all 512 threads; 32 threads/row, 4 cols each
    {
        int row = t >> 5, cb = (t & 31) * 4;
        float4 a4 = *(const float4*)&y[(long)(row0 + row) * HID + cb];
        float4 b4 = *(const float4*)&h[(long)(row0 + row) * HID + cb];
        float v[4] = {a4.x + b4.x, a4.y + b4.y, a4.z + b4.z, a4.w + b4.w};
        float s = v[0] + v[1] + v[2] + v[3];
        float s2 = v[0]*v[0] + v[1]*v[1] + v[2]*v[2] + v[3]*v[3];
        s  += __shfl_xor(s, 1);  s  += __shfl_xor(s, 2);  s  += __shfl_xor(s, 4);
        s  += __shfl_xor(s, 8);  s  += __shfl_xor(s, 16);
        s2 += __shfl_xor(s2, 1); s2 += __shfl_xor(s2, 2); s2 += __shfl_xor(s2, 4);
        s2 += __shfl_xor(s2, 8); s2 += __shfl_xor(s2, 16);
        float mu  = s * (1.f / HID);
        float var = s2 * (1.f / HID) - mu * mu;
        float inv = rsqrtf(var + 1e-5f);
        unsigned short hi4[4], lo4[4];
#pragma unroll
        for (int j = 0; j < 4; ++j) {
            int c = cb + j;
            float o = (v[j] - mu) * inv * g[c] + b[c];
            hi4[j] = f2b(o); lo4[j] = f2b(o - us2f(hi4[j]));
        }
        *(uint2*)&sAh[row * 136 + cb] = *(const uint2*)hi4;
        *(uint2*)&sAl[row * 136 + cb] = *(const uint2*)lo4;
    }
    __syncthreads();

    // ---- GEMM1: hid[16][512]; wave w -> k-cols [w*64, w*64+64). 48 MFMA/wave.
    f32x4 acc1[4];
#pragma unroll
    for (int i = 0; i < 4; ++i) acc1[i] = (f32x4){0.f, 0.f, 0.f, 0.f};
#pragma unroll
    for (int c = 0; c < 4; ++c) {
        bf16x8 ah = *(const bf16x8*)&sAh[m * 136 + c * 32 + quad * 8];
        bf16x8 al = *(const bf16x8*)&sAl[m * 136 + c * 32 + quad * 8];
#pragma unroll
        for (int nt = 0; nt < 4; ++nt) {
            bf16x8 wh = (c == 0) ? p1h[nt] : *(const bf16x8*)&w1h[nt * 16 * 128 + c * 32];
            bf16x8 wl = (c == 0) ? p1l[nt] : *(const bf16x8*)&w1l[nt * 16 * 128 + c * 32];
            acc1[nt] = __builtin_amdgcn_mfma_f32_16x16x32_bf16(wh, ah, acc1[nt], 0, 0, 0);
            acc1[nt] = __builtin_amdgcn_mfma_f32_16x16x32_bf16(wh, al, acc1[nt], 0, 0, 0);
            acc1[nt] = __builtin_amdgcn_mfma_f32_16x16x32_bf16(wl, ah, acc1[nt], 0, 0, 0);
        }
    }
    // relu + split + packed store: 4 consecutive k of row m per nt -> one 8B write per plane
#pragma unroll
    for (int nt = 0; nt < 4; ++nt) {
        unsigned short hi4[4], lo4[4];
#pragma unroll
        for (int r = 0; r < 4; ++r) {
            float v = fmaxf(acc1[nt][r], 0.f);
            hi4[r] = f2b(v);
            lo4[r] = f2b(v - us2f(hi4[r]));
        }
        int kk = w * 64 + nt * 16 + quad * 4;
        *(uint2*)&sHh[m * 520 + kk] = *(const uint2*)hi4;
        *(uint2*)&sHl[m * 520 + kk] = *(const uint2*)lo4;
    }

    // W2 fragment base; prefetch c=0,1 above the barrier (depth-2 pipeline)
    const unsigned short* w2h = W2H_ + (long)(w * 16 + m) * 512 + quad * 8;
    const unsigned short* w2l = W2L_ + (long)(w * 16 + m) * 512 + quad * 8;
    bf16x8 fh0 = *(const bf16x8*)w2h,        fl0 = *(const bf16x8*)w2l;
    bf16x8 fh1 = *(const bf16x8*)&w2h[32],   fl1 = *(const bf16x8*)&w2l[32];
    __syncthreads();

    // ---- GEMM2: out[16][128]; wave w -> cols [w*16, w*16+16). 48 MFMA, W prefetched 2 ahead.
    f32x4 acc2 = (f32x4){0.f, 0.f, 0.f, 0.f};
#pragma unroll
    for (int c = 0; c < 16; ++c) {
        bf16x8 wh = (c & 1) ? fh1 : fh0;
        bf16x8 wl = (c & 1) ? fl1 : fl0;
        if (c < 14) {
            if (c & 1) { fh1 = *(const bf16x8*)&w2h[(c + 2) * 32]; fl1 = *(const bf16x8*)&w2l[(c + 2) * 32]; }
            else       { fh0 = *(const bf16x8*)&w2h[(c + 2) * 32]; fl0 = *(const bf16x8*)&w2l[(c + 2) * 32]; }
        }
        bf16x8 ah = *(const bf16x8*)&sHh[m * 520 + c * 32 + quad * 8];
        bf16x8 al = *(const bf16x8*)&sHl[m * 520 + c * 32 + quad * 8];
        acc2 = __builtin_amdgcn_mfma_f32_16x16x32_bf16(ah, wh, acc2, 0, 0, 0);
        acc2 = __builtin_amdgcn_mfma_f32_16x16x32_bf16(ah, wl, acc2, 0, 0, 0);
        acc2 = __builtin_amdgcn_mfma_f32_16x16x32_bf16(al, wh, acc2, 0, 0, 0);
    }
    __syncthreads();                    // all sHh/sHl reads done; reuse as fp32 decode tile
    float* ht = (float*)&sHh[0];        // [16][132]
#pragma unroll
    for (int r = 0; r < 4; ++r) {
        int row = quad * 4 + r;
        int col = w * 16 + m;
        float v = acc2[r] + y[(long)(row0 + row) * HID + col];
        hout[(long)(row0 + row) * HID + col] = v;
        ht[row * 132 + col] = v;
    }
    __syncthreads();
    if (Wdec && t < 256) {              // fused decode: out = 10*tanh((h@Wdec)/sqrt(128))
        int row = t >> 4, sub = t & 15;
        float vv[8];
        *(float4*)&vv[0] = *(const float4*)&ht[row * 132 + sub * 8];
        *(float4*)&vv[4] = *(const float4*)&ht[row * 132 + sub * 8 + 4];
        float a = 0.f;
#pragma unroll
        for (int j = 0; j < 8; ++j) a += vv[j] * Wdec[sub * 8 + j];
        a += __shfl_xor(a, 1); a += __shfl_xor(a, 2); a += __shfl_xor(a, 4); a += __shfl_xor(a, 8);
        if (sub == 0) out[row0 + row] = 10.f * tanhf(a * 0.08838834764831845f);
    }
}

// ---------- attention: grid 512 = b x head x quarter; 4 waves x 16 q-rows.
// qkvT layout -> coalesced staging. QK^T PACKED: hi-parts in k=0..15, lo-parts in
// k=16..31 of the 16x16x32 MFMA -> full 4-term split product in 2 MFMAs (was 3),
// one K-frag LDS read per tile (was 2), all 64 lanes active.
#define PAS 268   // u16 stride, 134 dwords === 6 mod 32 -> bank-floor frag reads/stores
#define KQS 20    // u16 stride for K/Q planes, 10 dwords -> bank-floor frag reads
__global__ __launch_bounds__(256) void k_attn(
    const unsigned short* __restrict__ qkvH, const unsigned short* __restrict__ qkvL,
    const float* __restrict__ ef, const float* __restrict__ sbuf,
    int layer, float* __restrict__ y)
{
    __shared__ unsigned short Kh[NS * KQS], Kl[NS * KQS];    // [key][d]
    __shared__ unsigned short Qh[64 * KQS], Ql[64 * KQS];    // [qrow][d]
    __shared__ unsigned short Vh[16 * PAS], Vl[16 * PAS];    // [d][key]
    __shared__ unsigned short Pa[4][16 * PAS];               // per-wave [qrow][key]
    int bid = blockIdx.x;
    int q4 = bid & 3, hh = (bid >> 2) & 7, bb = bid >> 5;
    int t = threadIdx.x;
    {   // K,V staging from qkvT: thread (d = t>>4, keychunk = (t&15)*16): coalesced 32B runs
        int d = t >> 4, kc = (t & 15) * 16;
        long base = (long)ROWS * (HID + hh * 16 + d) + bb * NS + kc;
        long vbase = base + (long)ROWS * 128;
        union { uint4 u[2]; unsigned short s[16]; } KH, KL, VH, VL;
        KH.u[0] = *(const uint4*)&qkvH[base];      KH.u[1] = *(const uint4*)&qkvH[base + 8];
        KL.u[0] = *(const uint4*)&qkvL[base];      KL.u[1] = *(const uint4*)&qkvL[base + 8];
        VH.u[0] = *(const uint4*)&qkvH[vbase];     VH.u[1] = *(const uint4*)&qkvH[vbase + 8];
        VL.u[0] = *(const uint4*)&qkvL[vbase];     VL.u[1] = *(const uint4*)&qkvL[vbase + 8];
#pragma unroll
        for (int j = 0; j < 16; ++j) {             // K -> [key][d] (scatter)
            Kh[(kc + j) * KQS + d] = KH.s[j];
            Kl[(kc + j) * KQS + d] = KL.s[j];
        }
#pragma unroll
        for (int j = 0; j < 4; ++j) {              // V -> [d][key] (contiguous, vectorized)
            *(uint2*)&Vh[d * PAS + kc + j * 4] = *(const uint2*)&VH.s[j * 4];
            *(uint2*)&Vl[d * PAS + kc + j * 4] = *(const uint2*)&VL.s[j * 4];
        }
    }
    {   // Q staging from qkvT: thread (d = t>>4, rowchunk = (t&15)*4): coalesced 8B runs
        int d = t >> 4, rc = (t & 15) * 4;
        long qb = (long)ROWS * (hh * 16 + d) + bb * NS + q4 * 64 + rc;
        union { uint2 u; unsigned short s[4]; } QH, QL;
        QH.u = *(const uint2*)&qkvH[qb];
        QL.u = *(const uint2*)&qkvL[qb];
#pragma unroll
        for (int j = 0; j < 4; ++j) {
            Qh[(rc + j) * KQS + d] = QH.s[j];
            Ql[(rc + j) * KQS + d] = QL.s[j];
        }
    }
    __syncthreads();
    int w = t >> 6, lane = t & 63;
    int m = lane & 15, quad = lane >> 4;
    float s1  = sbuf[layer * 16 + hh];
    float s2g = sbuf[layer * 16 + NHEAD + hh];
    unsigned short* Paw = Pa[w];

    // Packed fragments: quads 0,1 hold hi-plane d=0..15 (k=0..15); quads 2,3 hold
    // lo-plane d=0..15 (k=16..31). qA=[qh|ql], qB=[ql|qh], kA=[kh|kl].
    const unsigned short* Qa = (quad < 2) ? Qh : Ql;
    const unsigned short* Qb = (quad < 2) ? Ql : Qh;
    const unsigned short* Ka = (quad < 2) ? Kh : Kl;
    int qoff = (w * 16 + m) * KQS + (quad & 1) * 8;
    bf16x8 qA = *(const bf16x8*)&Qa[qoff];
    bf16x8 qB = *(const bf16x8*)&Qb[qoff];
    // QK^T via MFMA: 16 col-tiles of 16 keys; 2 mfma each = full 4-term split product
    f32x4 sc[16];
#pragma unroll
    for (int ct = 0; ct < 16; ++ct) {
        bf16x8 kA = *(const bf16x8*)&Ka[(ct * 16 + m) * KQS + (quad & 1) * 8];
        f32x4 a = (f32x4){0.f, 0.f, 0.f, 0.f};
        a = __builtin_amdgcn_mfma_f32_16x16x32_bf16(qA, kA, a, 0, 0, 0);   // qh·kh + ql·kl
        a = __builtin_amdgcn_mfma_f32_16x16x32_bf16(qB, kA, a, 0, 0, 0);   // ql·kh + qh·kl
        sc[ct] = a;
    }
    // softmax, deferred normalization: Pa = p*e, running row-sums only (batched ef loads).
    int baserow = q4 * 64 + w * 16 + quad * 4;
    float s[4] = {0.f, 0.f, 0.f, 0.f};
#pragma unroll
    for (int ct = 0; ct < 16; ++ct) {
#pragma unroll
        for (int r = 0; r < 4; ++r) {
            float e = ef[((long)(bb * NS + baserow + r)) * NS + ct * 16 + m];
            float p = __expf(sc[ct][r] * 0.25f + e * s1);
            s[r] += p;
            Paw[(quad * 4 + r) * PAS + ct * 16 + m] = f2b(p * e);
        }
    }
    float inv[4];
#pragma unroll
    for (int r = 0; r < 4; ++r) {
        float ss = s[r];
        ss += __shfl_xor(ss, 1); ss += __shfl_xor(ss, 2);
        ss += __shfl_xor(ss, 4); ss += __shfl_xor(ss, 8);
        inv[r] = s2g / ss;
    }
    // no barrier: Pa is wave-private (same-wave LDS ops are in-order);
    // V/K were covered by the staging barrier above.
    f32x4 acc = (f32x4){0.f, 0.f, 0.f, 0.f};
#pragma unroll
    for (int sft = 0; sft < 8; ++sft) {
        bf16x8 pf = *(const bf16x8*)&Paw[m * PAS + sft * 32 + quad * 8];
        bf16x8 vh = *(const bf16x8*)&Vh[m * PAS + sft * 32 + quad * 8];
        bf16x8 vl = *(const bf16x8*)&Vl[m * PAS + sft * 32 + quad * 8];
        acc = __builtin_amdgcn_mfma_f32_16x16x32_bf16(pf, vh, acc, 0, 0, 0);
        acc = __builtin_amdgcn_mfma_f32_16x16x32_bf16(pf, vl, acc, 0, 0, 0);
    }
#pragma unroll
    for (int r = 0; r < 4; ++r) {
        int row = q4 * 64 + w * 16 + quad * 4 + r;
        y[((long)(bb * NS + row)) * HID + hh * 16 + m] = acc[r] * inv[r];
    }
}

extern "C" void kernel_launch(void* const* d_in, const int* in_sizes, int n_in,
                              void* d_out, int out_size, void* d_ws, size_t ws_size,
                              hipStream_t stream) {
    const float* nf    = (const float*)d_in[0];
    const float* ef    = (const float*)d_in[1];
    const float* Wn    = (const float*)d_in[2];
    const float* We_in = (const float*)d_in[3];
    const float* ln1g  = (const float*)d_in[4];
    const float* ln1b  = (const float*)d_in[5];
    const float* Wh    = (const float*)d_in[6];
    const float* We    = (const float*)d_in[7];
    const float* ln2g  = (const float*)d_in[8];
    const float* ln2b  = (const float*)d_in[9];
    const float* W1    = (const float*)d_in[10];
    const float* W2    = (const float*)d_in[11];
    const float* Wdec  = (const float*)d_in[12];

    float* ws   = (float*)d_ws;
    float* sbuf = ws;                            // 64 slots
    float* h    = ws + 64;                       // 4096*128
    float* y    = h + ROWS * HID;                // 4096*128
    unsigned short* qkvH = (unsigned short*)(y + ROWS * HID);   // TRANSPOSED [384][4096] u16
    unsigned short* qkvL = qkvH + (long)384 * ROWS;
    unsigned short* WhH  = qkvL + (long)384 * ROWS;             // 3*384*128
    unsigned short* WhL  = WhH + (long)NL * 384 * 128;
    unsigned short* W1H  = WhL + (long)NL * 384 * 128;          // 3*512*128
    unsigned short* W1L  = W1H + (long)NL * 512 * 128;
    unsigned short* W2H  = W1L + (long)NL * 512 * 128;          // 3*128*512
    unsigned short* W2L  = W2H + (long)NL * 128 * 512;

    k_prep<<<529 + ROWS * HID / 1024, 256, 0, stream>>>(Wh, W1, W2, We_in, We, nf, Wn,
                                    WhH, WhL, W1H, W1L, W2H, W2L, sbuf, h);
    for (int l = 0; l < NL; ++l) {
        // LN1 + QKV GEMM -> transposed split planes
        k_fgemm<<<dim3(6, 64), 256, 0, stream>>>(h, nullptr,
            ln1g + l * HID, ln1b + l * HID,
            WhH + (long)l * 384 * 128, WhL + (long)l * 384 * 128,
            qkvH, qkvL, 0);
        k_attn<<<512, 256, 0, stream>>>(qkvH, qkvL, ef, sbuf, l, y);
        // fused LN2 + W1 + relu + W2 + residual (+ decode on last layer)
        int last = (l == NL - 1);
        k_mlp<<<ROWS / 16, 512, 0, stream>>>(y, h,
            ln2g + l * HID, ln2b + l * HID,
            W1H + (long)l * 512 * 128, W1L + (long)l * 512 * 128,
            W2H + (long)l * 128 * 512, W2L + (long)l * 128 * 512,
            h, last ? Wdec : nullptr, (float*)d_out);
    }
}

// Round 7
// 202.776 us; speedup vs baseline: 1.0367x; 1.0367x over previous
//
#include <hip/hip_runtime.h>
#include <math.h>

#define HID 128
#define NHEAD 8
#define NL 3
#define NS 256
#define ROWS 4096

typedef __attribute__((ext_vector_type(8))) short bf16x8;
typedef __attribute__((ext_vector_type(4))) float f32x4;

__device__ __forceinline__ float us2f(unsigned short s) { return __uint_as_float(((unsigned)s) << 16); }
__device__ __forceinline__ unsigned short f2b(float f) {   // RNE fp32->bf16
    unsigned u = __float_as_uint(f);
    return (unsigned short)((u + 0x7fff + ((u >> 16) & 1)) >> 16);
}

// ---------- prep: weight split+transpose to bf16 hi/lo planes [N][K] + edge scalars + embed
// blocks: [0,144) Wh, [144,336) W1, [336,528) W2, 528 edge scalars, [529,1041) embed h=nf@Wn
__global__ __launch_bounds__(256) void k_prep(
    const float* __restrict__ Wh, const float* __restrict__ W1, const float* __restrict__ W2,
    const float* __restrict__ We_in, const float* __restrict__ We,
    const float* __restrict__ nf, const float* __restrict__ Wn,
    unsigned short* __restrict__ WhH, unsigned short* __restrict__ WhL,
    unsigned short* __restrict__ W1H, unsigned short* __restrict__ W1L,
    unsigned short* __restrict__ W2H, unsigned short* __restrict__ W2L,
    float* __restrict__ sbuf, float* __restrict__ h)
{
    int b = blockIdx.x, t = threadIdx.x;
    if (b >= 529) {                       // embed, vectorized: one float4 per thread
        int idx4 = (b - 529) * 256 + t;
        int r = idx4 >> 5, c4 = (idx4 & 31) * 4;
        float n0 = nf[2 * r], n1 = nf[2 * r + 1];
        float4 w0 = *(const float4*)&Wn[c4];
        float4 w1 = *(const float4*)&Wn[HID + c4];
        float4 o = {n0 * w0.x + n1 * w1.x, n0 * w0.y + n1 * w1.y,
                    n0 * w0.z + n1 * w1.z, n0 * w0.w + n1 * w1.w};
        *(float4*)&h[idx4 * 4] = o;
        return;
    }
    if (b == 528) {                       // edge scalars (rank-1 collapse of e @ We)
        if (t < NL * 2 * NHEAD) {
            int l = t / (2 * NHEAD), j = t % (2 * NHEAD);
            float acc = 0.f;
            for (int c = 0; c < HID; ++c)
                acc += We_in[c] * We[(long)(l * HID + c) * (2 * NHEAD) + j];
            sbuf[t] = acc;
        }
        return;
    }
    const float* S; unsigned short *OH, *OL; int K, N, kt, nt;
    if (b < 144) {
        int l = b / 48, rem = b % 48; kt = rem & 3; nt = rem >> 2; K = 128; N = 384;
        S = Wh + (long)l * 128 * 384; OH = WhH + (long)l * 384 * 128; OL = WhL + (long)l * 384 * 128;
    } else if (b < 336) {
        int b2 = b - 144; int l = b2 / 64, rem = b2 % 64; kt = rem & 3; nt = rem >> 2; K = 128; N = 512;
        S = W1 + (long)l * 128 * 512; OH = W1H + (long)l * 512 * 128; OL = W1L + (long)l * 512 * 128;
    } else {
        int b2 = b - 336; int l = b2 / 64, rem = b2 % 64; kt = rem & 15; nt = rem >> 4; K = 512; N = 128;
        S = W2 + (long)l * 512 * 128; OH = W2H + (long)l * 128 * 512; OL = W2L + (long)l * 128 * 512;
    }
    __shared__ float sm[32][33];
    int i0 = t >> 5, j = t & 31;
#pragma unroll
    for (int p = 0; p < 4; ++p) {
        int i = i0 + p * 8;
        sm[i][j] = S[(long)(kt * 32 + i) * N + nt * 32 + j];
    }
    __syncthreads();
#pragma unroll
    for (int p = 0; p < 4; ++p) {
        int n = i0 + p * 8;
        float v = sm[j][n];
        unsigned short hh = f2b(v);
        long o = (long)(nt * 32 + n) * K + kt * 32 + j;
        OH[o] = hh; OL[o] = f2b(v - us2f(hh));
    }
}

// ---------- fused LN + split-bf16 MFMA GEMM, K=128 single-shot, 64x64 tile, 4 waves.
// QKV producer. Output written TRANSPOSED: C^T[col][ROWS] — acc r=0..3 are consecutive
// rows of one col, so the transposed store packs into uint2 (8B) per plane.
__global__ __launch_bounds__(256) void k_fgemm(
    const float* __restrict__ x, const float* __restrict__ x2,
    const float* __restrict__ g, const float* __restrict__ b,
    const unsigned short* __restrict__ WH, const unsigned short* __restrict__ WL,
    unsigned short* __restrict__ Ch, unsigned short* __restrict__ Cl,
    int mode)
{
    __shared__ unsigned short sAh[64 * 136], sAl[64 * 136];   // [m][k]
    __shared__ unsigned short sWh[64 * 136], sWl[64 * 136];   // [n][k]
    int t = threadIdx.x;
    int row0 = blockIdx.y * 64, col0 = blockIdx.x * 64;

#pragma unroll
    for (int p = 0; p < 4; ++p) {
        int rr = (t >> 4) + p * 16, ck = t & 15;
        *(uint4*)&sWh[rr * 136 + ck * 8] = *(const uint4*)&WH[(long)(col0 + rr) * 128 + ck * 8];
        *(uint4*)&sWl[rr * 136 + ck * 8] = *(const uint4*)&WL[(long)(col0 + rr) * 128 + ck * 8];
    }
#pragma unroll
    for (int pass = 0; pass < 2; ++pass) {
        int row = pass * 32 + (t >> 3);
        int p = t & 7, cb = p * 16;
        float v[16];
        const float* xp = x + (long)(row0 + row) * HID + cb;
#pragma unroll
        for (int j = 0; j < 16; j += 4) *(float4*)&v[j] = *(const float4*)(xp + j);
        if (x2) {
            const float* yp = x2 + (long)(row0 + row) * HID + cb;
#pragma unroll
            for (int j = 0; j < 16; j += 4) {
                float4 r4 = *(const float4*)(yp + j);
                v[j] += r4.x; v[j+1] += r4.y; v[j+2] += r4.z; v[j+3] += r4.w;
            }
        }
        float s = 0.f, s2 = 0.f;
#pragma unroll
        for (int j = 0; j < 16; ++j) { s += v[j]; s2 += v[j] * v[j]; }
        s  += __shfl_xor(s, 1);  s  += __shfl_xor(s, 2);  s  += __shfl_xor(s, 4);
        s2 += __shfl_xor(s2, 1); s2 += __shfl_xor(s2, 2); s2 += __shfl_xor(s2, 4);
        float mu  = s * (1.f / HID);
        float var = s2 * (1.f / HID) - mu * mu;
        float inv = rsqrtf(var + 1e-5f);
        unsigned short hi[16], lo[16];
#pragma unroll
        for (int j = 0; j < 16; ++j) {
            int c = cb + j;
            float o = (v[j] - mu) * inv * g[c] + b[c];
            hi[j] = f2b(o); lo[j] = f2b(o - us2f(hi[j]));
        }
        *(uint4*)&sAh[row * 136 + cb]     = *(uint4*)&hi[0];
        *(uint4*)&sAh[row * 136 + cb + 8] = *(uint4*)&hi[8];
        *(uint4*)&sAl[row * 136 + cb]     = *(uint4*)&lo[0];
        *(uint4*)&sAl[row * 136 + cb + 8] = *(uint4*)&lo[8];
    }
    __syncthreads();

    int w = t >> 6, lane = t & 63;
    int m = lane & 15, quad = lane >> 4;
    f32x4 acc[4];
#pragma unroll
    for (int i = 0; i < 4; ++i) acc[i] = (f32x4){0.f, 0.f, 0.f, 0.f};
#pragma unroll
    for (int c = 0; c < 4; ++c) {
        bf16x8 ah = *(const bf16x8*)&sAh[(w * 16 + m) * 136 + c * 32 + quad * 8];
        bf16x8 al = *(const bf16x8*)&sAl[(w * 16 + m) * 136 + c * 32 + quad * 8];
#pragma unroll
        for (int nt = 0; nt < 4; ++nt) {
            bf16x8 wh = *(const bf16x8*)&sWh[(nt * 16 + m) * 136 + c * 32 + quad * 8];
            bf16x8 wl = *(const bf16x8*)&sWl[(nt * 16 + m) * 136 + c * 32 + quad * 8];
            acc[nt] = __builtin_amdgcn_mfma_f32_16x16x32_bf16(ah, wh, acc[nt], 0, 0, 0);
            acc[nt] = __builtin_amdgcn_mfma_f32_16x16x32_bf16(ah, wl, acc[nt], 0, 0, 0);
            acc[nt] = __builtin_amdgcn_mfma_f32_16x16x32_bf16(al, wh, acc[nt], 0, 0, 0);
        }
    }
    // transposed epilogue: lane holds rows quad*4..+3 of col nt*16+m -> packed uint2
#pragma unroll
    for (int nt = 0; nt < 4; ++nt) {
        unsigned short hi4[4], lo4[4];
#pragma unroll
        for (int r = 0; r < 4; ++r) {
            float v = acc[nt][r];
            if (mode) v = fmaxf(v, 0.f);
            hi4[r] = f2b(v); lo4[r] = f2b(v - us2f(hi4[r]));
        }
        long o = (long)(col0 + nt * 16 + m) * ROWS + row0 + w * 16 + quad * 4;
        *(uint2*)&Ch[o] = *(const uint2*)hi4;
        *(uint2*)&Cl[o] = *(const uint2*)lo4;
    }
}

// ---------- fused MLP: LN2(y+h) -> W1 GEMM + relu -> W2 GEMM + residual (+decode).
// 512 threads / 8 waves (2 waves/SIMD); 16 rows/block, 256 blocks. (R2/R5-proven form)
__global__ __launch_bounds__(512, 1) void k_mlp(
    const float* __restrict__ y, const float* __restrict__ h,
    const float* __restrict__ g, const float* __restrict__ b,
    const unsigned short* __restrict__ W1H_, const unsigned short* __restrict__ W1L_,
    const unsigned short* __restrict__ W2H_, const unsigned short* __restrict__ W2L_,
    float* __restrict__ hout, const float* __restrict__ Wdec, float* __restrict__ out)
{
    __shared__ __align__(16) unsigned short sAh[16 * 136], sAl[16 * 136];   // LN2 out planes [row][k]
    __shared__ __align__(16) unsigned short sHh[16 * 520], sHl[16 * 520];   // hid planes [row][k], k=512
    int t = threadIdx.x;
    int row0 = blockIdx.x * 16;
    int w = t >> 6, lane = t & 63;
    int m = lane & 15, quad = lane >> 4;

    // W1 fragment base for this wave's k-slab; prefetch c=0 fragments above the barrier
    const unsigned short* w1h = W1H_ + (long)(w * 64 + m) * 128 + quad * 8;
    const unsigned short* w1l = W1L_ + (long)(w * 64 + m) * 128 + quad * 8;
    bf16x8 p1h[4], p1l[4];
#pragma unroll
    for (int nt = 0; nt < 4; ++nt) {
        p1h[nt] = *(const bf16x8*)&w1h[nt * 16 * 128];
        p1l[nt] = *(const bf16x8*)&w1l[nt * 16 * 128];
    }

    // ---- LN2(y + h): all 512 threads; 32 threads/row, 4 cols each
    {
        int row = t >> 5, cb = (t & 31) * 4;
        float4 a4 = *(const float4*)&y[(long)(row0 + row) * HID + cb];
        float4 b4 = *(const float4*)&h[(long)(row0 + row) * HID + cb];
        float v[4] = {a4.x + b4.x, a4.y + b4.y, a4.z + b4.z, a4.w + b4.w};
        float s = v[0] + v[1] + v[2] + v[3];
        float s2 = v[0]*v[0] + v[1]*v[1] + v[2]*v[2] + v[3]*v[3];
        s  += __shfl_xor(s, 1);  s  += __shfl_xor(s, 2);  s  += __shfl_xor(s, 4);
        s  += __shfl_xor(s, 8);  s  += __shfl_xor(s, 16);
        s2 += __shfl_xor(s2, 1); s2 += __shfl_xor(s2, 2); s2 += __shfl_xor(s2, 4);
        s2 += __shfl_xor(s2, 8); s2 += __shfl_xor(s2, 16);
        float mu  = s * (1.f / HID);
        float var = s2 * (1.f / HID) - mu * mu;
        float inv = rsqrtf(var + 1e-5f);
        unsigned short hi4[4], lo4[4];
#pragma unroll
        for (int j = 0; j < 4; ++j) {
            int c = cb + j;
            float o = (v[j] - mu) * inv * g[c] + b[c];
            hi4[j] = f2b(o); lo4[j] = f2b(o - us2f(hi4[j]));
        }
        *(uint2*)&sAh[row * 136 + cb] = *(const uint2*)hi4;
        *(uint2*)&sAl[row * 136 + cb] = *(const uint2*)lo4;
    }
    __syncthreads();

    // ---- GEMM1: hid[16][512]; wave w -> k-cols [w*64, w*64+64). 48 MFMA/wave.
    f32x4 acc1[4];
#pragma unroll
    for (int i = 0; i < 4; ++i) acc1[i] = (f32x4){0.f, 0.f, 0.f, 0.f};
#pragma unroll
    for (int c = 0; c < 4; ++c) {
        bf16x8 ah = *(const bf16x8*)&sAh[m * 136 + c * 32 + quad * 8];
        bf16x8 al = *(const bf16x8*)&sAl[m * 136 + c * 32 + quad * 8];
#pragma unroll
        for (int nt = 0; nt < 4; ++nt) {
            bf16x8 wh = (c == 0) ? p1h[nt] : *(const bf16x8*)&w1h[nt * 16 * 128 + c * 32];
            bf16x8 wl = (c == 0) ? p1l[nt] : *(const bf16x8*)&w1l[nt * 16 * 128 + c * 32];
            acc1[nt] = __builtin_amdgcn_mfma_f32_16x16x32_bf16(wh, ah, acc1[nt], 0, 0, 0);
            acc1[nt] = __builtin_amdgcn_mfma_f32_16x16x32_bf16(wh, al, acc1[nt], 0, 0, 0);
            acc1[nt] = __builtin_amdgcn_mfma_f32_16x16x32_bf16(wl, ah, acc1[nt], 0, 0, 0);
        }
    }
    // relu + split + packed store: 4 consecutive k of row m per nt -> one 8B write per plane
#pragma unroll
    for (int nt = 0; nt < 4; ++nt) {
        unsigned short hi4[4], lo4[4];
#pragma unroll
        for (int r = 0; r < 4; ++r) {
            float v = fmaxf(acc1[nt][r], 0.f);
            hi4[r] = f2b(v);
            lo4[r] = f2b(v - us2f(hi4[r]));
        }
        int kk = w * 64 + nt * 16 + quad * 4;
        *(uint2*)&sHh[m * 520 + kk] = *(const uint2*)hi4;
        *(uint2*)&sHl[m * 520 + kk] = *(const uint2*)lo4;
    }

    // W2 fragment base; prefetch c=0 above the barrier
    const unsigned short* w2h = W2H_ + (long)(w * 16 + m) * 512 + quad * 8;
    const unsigned short* w2l = W2L_ + (long)(w * 16 + m) * 512 + quad * 8;
    bf16x8 p2h = *(const bf16x8*)w2h;
    bf16x8 p2l = *(const bf16x8*)w2l;
    __syncthreads();

    // ---- GEMM2: out[16][128]; wave w -> cols [w*16, w*16+16). 48 MFMA/wave.
    f32x4 acc2 = (f32x4){0.f, 0.f, 0.f, 0.f};
#pragma unroll
    for (int c = 0; c < 16; ++c) {
        bf16x8 ah = *(const bf16x8*)&sHh[m * 520 + c * 32 + quad * 8];
        bf16x8 al = *(const bf16x8*)&sHl[m * 520 + c * 32 + quad * 8];
        bf16x8 wh = (c == 0) ? p2h : *(const bf16x8*)&w2h[c * 32];
        bf16x8 wl = (c == 0) ? p2l : *(const bf16x8*)&w2l[c * 32];
        acc2 = __builtin_amdgcn_mfma_f32_16x16x32_bf16(ah, wh, acc2, 0, 0, 0);
        acc2 = __builtin_amdgcn_mfma_f32_16x16x32_bf16(ah, wl, acc2, 0, 0, 0);
        acc2 = __builtin_amdgcn_mfma_f32_16x16x32_bf16(al, wh, acc2, 0, 0, 0);
    }
    __syncthreads();                    // all sHh/sHl reads done; reuse as fp32 decode tile
    float* ht = (float*)&sHh[0];        // [16][132]
#pragma unroll
    for (int r = 0; r < 4; ++r) {
        int row = quad * 4 + r;
        int col = w * 16 + m;
        float v = acc2[r] + y[(long)(row0 + row) * HID + col];
        hout[(long)(row0 + row) * HID + col] = v;
        ht[row * 132 + col] = v;
    }
    __syncthreads();
    if (Wdec && t < 256) {              // fused decode: out = 10*tanh((h@Wdec)/sqrt(128))
        int row = t >> 4, sub = t & 15;
        float vv[8];
        *(float4*)&vv[0] = *(const float4*)&ht[row * 132 + sub * 8];
        *(float4*)&vv[4] = *(const float4*)&ht[row * 132 + sub * 8 + 4];
        float a = 0.f;
#pragma unroll
        for (int j = 0; j < 8; ++j) a += vv[j] * Wdec[sub * 8 + j];
        a += __shfl_xor(a, 1); a += __shfl_xor(a, 2); a += __shfl_xor(a, 4); a += __shfl_xor(a, 8);
        if (sub == 0) out[row0 + row] = 10.f * tanhf(a * 0.08838834764831845f);
    }
}

// ---------- attention: grid 512 = b x head x quarter; 4 waves x 16 q-rows.
// qkv arrives TRANSPOSED [384][4096] -> fully coalesced staging loads; V LDS writes
// vectorized. Softmax in batch form (64 ef loads issued together = max MLP).
#define PAS 268   // u16 stride, 134 dwords === 6 mod 32 -> bank-floor frag reads/stores
#define KQS 20    // u16 stride for K/Q planes, 10 dwords -> bank-floor frag reads
__global__ __launch_bounds__(256) void k_attn(
    const unsigned short* __restrict__ qkvH, const unsigned short* __restrict__ qkvL,
    const float* __restrict__ ef, const float* __restrict__ sbuf,
    int layer, float* __restrict__ y)
{
    __shared__ unsigned short Kh[NS * KQS], Kl[NS * KQS];    // [key][d]
    __shared__ unsigned short Qh[64 * KQS], Ql[64 * KQS];    // [qrow][d]
    __shared__ unsigned short Vh[16 * PAS], Vl[16 * PAS];    // [d][key]
    __shared__ unsigned short Pa[4][16 * PAS];               // per-wave [qrow][key]
    int bid = blockIdx.x;
    int q4 = bid & 3, hh = (bid >> 2) & 7, bb = bid >> 5;
    int t = threadIdx.x;
    {   // K,V staging from qkvT: thread (d = t>>4, keychunk = (t&15)*16): coalesced 32B runs
        int d = t >> 4, kc = (t & 15) * 16;
        long base = (long)ROWS * (HID + hh * 16 + d) + bb * NS + kc;
        long vbase = base + (long)ROWS * 128;
        union { uint4 u[2]; unsigned short s[16]; } KH, KL, VH, VL;
        KH.u[0] = *(const uint4*)&qkvH[base];      KH.u[1] = *(const uint4*)&qkvH[base + 8];
        KL.u[0] = *(const uint4*)&qkvL[base];      KL.u[1] = *(const uint4*)&qkvL[base + 8];
        VH.u[0] = *(const uint4*)&qkvH[vbase];     VH.u[1] = *(const uint4*)&qkvH[vbase + 8];
        VL.u[0] = *(const uint4*)&qkvL[vbase];     VL.u[1] = *(const uint4*)&qkvL[vbase + 8];
#pragma unroll
        for (int j = 0; j < 16; ++j) {             // K -> [key][d] (scatter)
            Kh[(kc + j) * KQS + d] = KH.s[j];
            Kl[(kc + j) * KQS + d] = KL.s[j];
        }
#pragma unroll
        for (int j = 0; j < 4; ++j) {              // V -> [d][key] (contiguous, vectorized)
            *(uint2*)&Vh[d * PAS + kc + j * 4] = *(const uint2*)&VH.s[j * 4];
            *(uint2*)&Vl[d * PAS + kc + j * 4] = *(const uint2*)&VL.s[j * 4];
        }
    }
    {   // Q staging from qkvT: thread (d = t>>4, rowchunk = (t&15)*4): coalesced 8B runs
        int d = t >> 4, rc = (t & 15) * 4;
        long qb = (long)ROWS * (hh * 16 + d) + bb * NS + q4 * 64 + rc;
        union { uint2 u; unsigned short s[4]; } QH, QL;
        QH.u = *(const uint2*)&qkvH[qb];
        QL.u = *(const uint2*)&qkvL[qb];
#pragma unroll
        for (int j = 0; j < 4; ++j) {
            Qh[(rc + j) * KQS + d] = QH.s[j];
            Ql[(rc + j) * KQS + d] = QL.s[j];
        }
    }
    __syncthreads();
    int w = t >> 6, lane = t & 63;
    int m = lane & 15, quad = lane >> 4;
    float s1  = sbuf[layer * 16 + hh];
    float s2g = sbuf[layer * 16 + NHEAD + hh];
    unsigned short* Paw = Pa[w];

    // Q A-fragment (once per wave): quads 2,3 = zero pad (k 16..31)
    bf16x8 qh = (bf16x8){0,0,0,0,0,0,0,0}, ql = qh;
    if (quad < 2) {
        qh = *(const bf16x8*)&Qh[(w * 16 + m) * KQS + quad * 8];
        ql = *(const bf16x8*)&Ql[(w * 16 + m) * KQS + quad * 8];
    }
    // QK^T via MFMA: 16 col-tiles of 16 keys
    f32x4 sc[16];
#pragma unroll
    for (int ct = 0; ct < 16; ++ct) {
        bf16x8 kh = (bf16x8){0,0,0,0,0,0,0,0}, kl = kh;
        if (quad < 2) {
            kh = *(const bf16x8*)&Kh[(ct * 16 + m) * KQS + quad * 8];
            kl = *(const bf16x8*)&Kl[(ct * 16 + m) * KQS + quad * 8];
        }
        f32x4 a = (f32x4){0.f, 0.f, 0.f, 0.f};
        a = __builtin_amdgcn_mfma_f32_16x16x32_bf16(qh, kh, a, 0, 0, 0);
        a = __builtin_amdgcn_mfma_f32_16x16x32_bf16(qh, kl, a, 0, 0, 0);
        a = __builtin_amdgcn_mfma_f32_16x16x32_bf16(ql, kh, a, 0, 0, 0);
        sc[ct] = a;
    }
    // softmax, deferred normalization: Pa = p*e, running row-sums only (batched ef loads).
    int baserow = q4 * 64 + w * 16 + quad * 4;
    float s[4] = {0.f, 0.f, 0.f, 0.f};
#pragma unroll
    for (int ct = 0; ct < 16; ++ct) {
#pragma unroll
        for (int r = 0; r < 4; ++r) {
            float e = ef[((long)(bb * NS + baserow + r)) * NS + ct * 16 + m];
            float p = __expf(sc[ct][r] * 0.25f + e * s1);
            s[r] += p;
            Paw[(quad * 4 + r) * PAS + ct * 16 + m] = f2b(p * e);
        }
    }
    float inv[4];
#pragma unroll
    for (int r = 0; r < 4; ++r) {
        float ss = s[r];
        ss += __shfl_xor(ss, 1); ss += __shfl_xor(ss, 2);
        ss += __shfl_xor(ss, 4); ss += __shfl_xor(ss, 8);
        inv[r] = s2g / ss;
    }
    // no barrier: Pa is wave-private (same-wave LDS ops are in-order);
    // V/K were covered by the staging barrier above.
    f32x4 acc = (f32x4){0.f, 0.f, 0.f, 0.f};
#pragma unroll
    for (int sft = 0; sft < 8; ++sft) {
        bf16x8 pf = *(const bf16x8*)&Paw[m * PAS + sft * 32 + quad * 8];
        bf16x8 vh = *(const bf16x8*)&Vh[m * PAS + sft * 32 + quad * 8];
        bf16x8 vl = *(const bf16x8*)&Vl[m * PAS + sft * 32 + quad * 8];
        acc = __builtin_amdgcn_mfma_f32_16x16x32_bf16(pf, vh, acc, 0, 0, 0);
        acc = __builtin_amdgcn_mfma_f32_16x16x32_bf16(pf, vl, acc, 0, 0, 0);
    }
#pragma unroll
    for (int r = 0; r < 4; ++r) {
        int row = q4 * 64 + w * 16 + quad * 4 + r;
        y[((long)(bb * NS + row)) * HID + hh * 16 + m] = acc[r] * inv[r];
    }
}

extern "C" void kernel_launch(void* const* d_in, const int* in_sizes, int n_in,
                              void* d_out, int out_size, void* d_ws, size_t ws_size,
                              hipStream_t stream) {
    const float* nf    = (const float*)d_in[0];
    const float* ef    = (const float*)d_in[1];
    const float* Wn    = (const float*)d_in[2];
    const float* We_in = (const float*)d_in[3];
    const float* ln1g  = (const float*)d_in[4];
    const float* ln1b  = (const float*)d_in[5];
    const float* Wh    = (const float*)d_in[6];
    const float* We    = (const float*)d_in[7];
    const float* ln2g  = (const float*)d_in[8];
    const float* ln2b  = (const float*)d_in[9];
    const float* W1    = (const float*)d_in[10];
    const float* W2    = (const float*)d_in[11];
    const float* Wdec  = (const float*)d_in[12];

    float* ws   = (float*)d_ws;
    float* sbuf = ws;                            // 64 slots
    float* h    = ws + 64;                       // 4096*128
    float* y    = h + ROWS * HID;                // 4096*128
    unsigned short* qkvH = (unsigned short*)(y + ROWS * HID);   // TRANSPOSED [384][4096] u16
    unsigned short* qkvL = qkvH + (long)384 * ROWS;
    unsigned short* WhH  = qkvL + (long)384 * ROWS;             // 3*384*128
    unsigned short* WhL  = WhH + (long)NL * 384 * 128;
    unsigned short* W1H  = WhL + (long)NL * 384 * 128;          // 3*512*128
    unsigned short* W1L  = W1H + (long)NL * 512 * 128;
    unsigned short* W2H  = W1L + (long)NL * 512 * 128;          // 3*128*512
    unsigned short* W2L  = W2H + (long)NL * 128 * 512;

    k_prep<<<529 + ROWS * HID / 1024, 256, 0, stream>>>(Wh, W1, W2, We_in, We, nf, Wn,
                                    WhH, WhL, W1H, W1L, W2H, W2L, sbuf, h);
    for (int l = 0; l < NL; ++l) {
        // LN1 + QKV GEMM -> transposed split planes
        k_fgemm<<<dim3(6, 64), 256, 0, stream>>>(h, nullptr,
            ln1g + l * HID, ln1b + l * HID,
            WhH + (long)l * 384 * 128, WhL + (long)l * 384 * 128,
            qkvH, qkvL, 0);
        k_attn<<<512, 256, 0, stream>>>(qkvH, qkvL, ef, sbuf, l, y);
        // fused LN2 + W1 + relu + W2 + residual (+ decode on last layer)
        int last = (l == NL - 1);
        k_mlp<<<ROWS / 16, 512, 0, stream>>>(y, h,
            ln2g + l * HID, ln2b + l * HID,
            W1H + (long)l * 512 * 128, W1L + (long)l * 512 * 128,
            W2H + (long)l * 128 * 512, W2L + (long)l * 128 * 512,
            h, last ? Wdec : nullptr, (float*)d_out);
    }
}

// Round 8
// 199.865 us; speedup vs baseline: 1.0518x; 1.0146x over previous
//
#include <hip/hip_runtime.h>
#include <math.h>

#define HID 128
#define NHEAD 8
#define NL 3
#define NS 256
#define ROWS 4096

typedef __attribute__((ext_vector_type(8))) short bf16x8;
typedef __attribute__((ext_vector_type(4))) float f32x4;

__device__ __forceinline__ float us2f(unsigned short s) { return __uint_as_float(((unsigned)s) << 16); }
__device__ __forceinline__ unsigned short f2b(float f) {   // RNE fp32->bf16
    unsigned u = __float_as_uint(f);
    return (unsigned short)((u + 0x7fff + ((u >> 16) & 1)) >> 16);
}

// ---------- prep: weight split+transpose to bf16 hi/lo planes [N][K] + edge scalars
// + embed h=nf@Wn (+ LN1 for layer 0 -> pre-LN'd A planes).
// blocks: [0,144) Wh, [144,336) W1, [336,528) W2, 528 edge scalars, [529,1041) embed
__global__ __launch_bounds__(256) void k_prep(
    const float* __restrict__ Wh, const float* __restrict__ W1, const float* __restrict__ W2,
    const float* __restrict__ We_in, const float* __restrict__ We,
    const float* __restrict__ nf, const float* __restrict__ Wn,
    const float* __restrict__ ln1g, const float* __restrict__ ln1b,
    unsigned short* __restrict__ WhH, unsigned short* __restrict__ WhL,
    unsigned short* __restrict__ W1H, unsigned short* __restrict__ W1L,
    unsigned short* __restrict__ W2H, unsigned short* __restrict__ W2L,
    unsigned short* __restrict__ AH, unsigned short* __restrict__ AL,
    float* __restrict__ sbuf, float* __restrict__ h)
{
    int b = blockIdx.x, t = threadIdx.x;
    if (b >= 529) {                       // embed + LN1(layer0): 32 threads/row, 4 cols each
        int idx4 = (b - 529) * 256 + t;
        int r = idx4 >> 5, c4 = (idx4 & 31) * 4;
        float n0 = nf[2 * r], n1 = nf[2 * r + 1];
        float4 w0 = *(const float4*)&Wn[c4];
        float4 w1 = *(const float4*)&Wn[HID + c4];
        float v[4] = {n0 * w0.x + n1 * w1.x, n0 * w0.y + n1 * w1.y,
                      n0 * w0.z + n1 * w1.z, n0 * w0.w + n1 * w1.w};
        *(float4*)&h[idx4 * 4] = *(float4*)v;
        float s = v[0] + v[1] + v[2] + v[3];
        float s2 = v[0]*v[0] + v[1]*v[1] + v[2]*v[2] + v[3]*v[3];
        s  += __shfl_xor(s, 1);  s  += __shfl_xor(s, 2);  s  += __shfl_xor(s, 4);
        s  += __shfl_xor(s, 8);  s  += __shfl_xor(s, 16);
        s2 += __shfl_xor(s2, 1); s2 += __shfl_xor(s2, 2); s2 += __shfl_xor(s2, 4);
        s2 += __shfl_xor(s2, 8); s2 += __shfl_xor(s2, 16);
        float mu  = s * (1.f / HID);
        float var = s2 * (1.f / HID) - mu * mu;
        float inv = rsqrtf(var + 1e-5f);
        unsigned short hi4[4], lo4[4];
#pragma unroll
        for (int j = 0; j < 4; ++j) {
            int c = c4 + j;
            float o = (v[j] - mu) * inv * ln1g[c] + ln1b[c];
            hi4[j] = f2b(o); lo4[j] = f2b(o - us2f(hi4[j]));
        }
        *(uint2*)&AH[(long)r * HID + c4] = *(const uint2*)hi4;
        *(uint2*)&AL[(long)r * HID + c4] = *(const uint2*)lo4;
        return;
    }
    if (b == 528) {                       // edge scalars (rank-1 collapse of e @ We)
        if (t < NL * 2 * NHEAD) {
            int l = t / (2 * NHEAD), j = t % (2 * NHEAD);
            float acc = 0.f;
            for (int c = 0; c < HID; ++c)
                acc += We_in[c] * We[(long)(l * HID + c) * (2 * NHEAD) + j];
            sbuf[t] = acc;
        }
        return;
    }
    const float* S; unsigned short *OH, *OL; int K, N, kt, nt;
    if (b < 144) {
        int l = b / 48, rem = b % 48; kt = rem & 3; nt = rem >> 2; K = 128; N = 384;
        S = Wh + (long)l * 128 * 384; OH = WhH + (long)l * 384 * 128; OL = WhL + (long)l * 384 * 128;
    } else if (b < 336) {
        int b2 = b - 144; int l = b2 / 64, rem = b2 % 64; kt = rem & 3; nt = rem >> 2; K = 128; N = 512;
        S = W1 + (long)l * 128 * 512; OH = W1H + (long)l * 512 * 128; OL = W1L + (long)l * 512 * 128;
    } else {
        int b2 = b - 336; int l = b2 / 64, rem = b2 % 64; kt = rem & 15; nt = rem >> 4; K = 512; N = 128;
        S = W2 + (long)l * 512 * 128; OH = W2H + (long)l * 128 * 512; OL = W2L + (long)l * 128 * 512;
    }
    __shared__ float sm[32][33];
    int i0 = t >> 5, j = t & 31;
#pragma unroll
    for (int p = 0; p < 4; ++p) {
        int i = i0 + p * 8;
        sm[i][j] = S[(long)(kt * 32 + i) * N + nt * 32 + j];
    }
    __syncthreads();
#pragma unroll
    for (int p = 0; p < 4; ++p) {
        int n = i0 + p * 8;
        float v = sm[j][n];
        unsigned short hh = f2b(v);
        long o = (long)(nt * 32 + n) * K + kt * 32 + j;
        OH[o] = hh; OL[o] = f2b(v - us2f(hh));
    }
}

// ---------- pure split-bf16 MFMA GEMM on pre-LN'd A planes, K=128, 64x64 tile, 4 waves.
// QKV producer. Output TRANSPOSED C^T[col][ROWS]; packed uint2 epilogue.
__global__ __launch_bounds__(256) void k_fgemm(
    const unsigned short* __restrict__ AH, const unsigned short* __restrict__ AL,
    const unsigned short* __restrict__ WH, const unsigned short* __restrict__ WL,
    unsigned short* __restrict__ Ch, unsigned short* __restrict__ Cl)
{
    __shared__ unsigned short sAh[64 * 136], sAl[64 * 136];   // [m][k]
    __shared__ unsigned short sWh[64 * 136], sWl[64 * 136];   // [n][k]
    int t = threadIdx.x;
    int row0 = blockIdx.y * 64, col0 = blockIdx.x * 64;

#pragma unroll
    for (int p = 0; p < 4; ++p) {
        int rr = (t >> 4) + p * 16, ck = t & 15;
        *(uint4*)&sWh[rr * 136 + ck * 8] = *(const uint4*)&WH[(long)(col0 + rr) * 128 + ck * 8];
        *(uint4*)&sWl[rr * 136 + ck * 8] = *(const uint4*)&WL[(long)(col0 + rr) * 128 + ck * 8];
        *(uint4*)&sAh[rr * 136 + ck * 8] = *(const uint4*)&AH[(long)(row0 + rr) * 128 + ck * 8];
        *(uint4*)&sAl[rr * 136 + ck * 8] = *(const uint4*)&AL[(long)(row0 + rr) * 128 + ck * 8];
    }
    __syncthreads();

    int w = t >> 6, lane = t & 63;
    int m = lane & 15, quad = lane >> 4;
    f32x4 acc[4];
#pragma unroll
    for (int i = 0; i < 4; ++i) acc[i] = (f32x4){0.f, 0.f, 0.f, 0.f};
#pragma unroll
    for (int c = 0; c < 4; ++c) {
        bf16x8 ah = *(const bf16x8*)&sAh[(w * 16 + m) * 136 + c * 32 + quad * 8];
        bf16x8 al = *(const bf16x8*)&sAl[(w * 16 + m) * 136 + c * 32 + quad * 8];
#pragma unroll
        for (int nt = 0; nt < 4; ++nt) {
            bf16x8 wh = *(const bf16x8*)&sWh[(nt * 16 + m) * 136 + c * 32 + quad * 8];
            bf16x8 wl = *(const bf16x8*)&sWl[(nt * 16 + m) * 136 + c * 32 + quad * 8];
            acc[nt] = __builtin_amdgcn_mfma_f32_16x16x32_bf16(ah, wh, acc[nt], 0, 0, 0);
            acc[nt] = __builtin_amdgcn_mfma_f32_16x16x32_bf16(ah, wl, acc[nt], 0, 0, 0);
            acc[nt] = __builtin_amdgcn_mfma_f32_16x16x32_bf16(al, wh, acc[nt], 0, 0, 0);
        }
    }
    // transposed epilogue: lane holds rows quad*4..+3 of col nt*16+m -> packed uint2
#pragma unroll
    for (int nt = 0; nt < 4; ++nt) {
        unsigned short hi4[4], lo4[4];
#pragma unroll
        for (int r = 0; r < 4; ++r) {
            float v = acc[nt][r];
            hi4[r] = f2b(v); lo4[r] = f2b(v - us2f(hi4[r]));
        }
        long o = (long)(col0 + nt * 16 + m) * ROWS + row0 + w * 16 + quad * 4;
        *(uint2*)&Ch[o] = *(const uint2*)hi4;
        *(uint2*)&Cl[o] = *(const uint2*)lo4;
    }
}

// ---------- fused MLP: LN2(y+h) -> W1 GEMM + relu -> W2 GEMM + residual
// + (non-last) LN1 of next layer -> A planes | (last) fused decode.
// 512 threads / 8 waves; 16 rows/block, 256 blocks.
__global__ __launch_bounds__(512, 1) void k_mlp(
    const float* __restrict__ y, const float* __restrict__ h,
    const float* __restrict__ g, const float* __restrict__ b,
    const float* __restrict__ lng, const float* __restrict__ lnb,
    const unsigned short* __restrict__ W1H_, const unsigned short* __restrict__ W1L_,
    const unsigned short* __restrict__ W2H_, const unsigned short* __restrict__ W2L_,
    float* __restrict__ hout,
    unsigned short* __restrict__ AHo, unsigned short* __restrict__ ALo,
    const float* __restrict__ Wdec, float* __restrict__ out)
{
    __shared__ __align__(16) unsigned short sAh[16 * 136], sAl[16 * 136];   // LN2 out planes [row][k]
    __shared__ __align__(16) unsigned short sHh[16 * 520], sHl[16 * 520];   // hid planes [row][k], k=512
    int t = threadIdx.x;
    int row0 = blockIdx.x * 16;
    int w = t >> 6, lane = t & 63;
    int m = lane & 15, quad = lane >> 4;

    // W1 fragment base for this wave's k-slab; prefetch c=0 fragments above the barrier
    const unsigned short* w1h = W1H_ + (long)(w * 64 + m) * 128 + quad * 8;
    const unsigned short* w1l = W1L_ + (long)(w * 64 + m) * 128 + quad * 8;
    bf16x8 p1h[4], p1l[4];
#pragma unroll
    for (int nt = 0; nt < 4; ++nt) {
        p1h[nt] = *(const bf16x8*)&w1h[nt * 16 * 128];
        p1l[nt] = *(const bf16x8*)&w1l[nt * 16 * 128];
    }

    // ---- LN2(y + h): all 512 threads; 32 threads/row, 4 cols each
    {
        int row = t >> 5, cb = (t & 31) * 4;
        float4 a4 = *(const float4*)&y[(long)(row0 + row) * HID + cb];
        float4 b4 = *(const float4*)&h[(long)(row0 + row) * HID + cb];
        float v[4] = {a4.x + b4.x, a4.y + b4.y, a4.z + b4.z, a4.w + b4.w};
        float s = v[0] + v[1] + v[2] + v[3];
        float s2 = v[0]*v[0] + v[1]*v[1] + v[2]*v[2] + v[3]*v[3];
        s  += __shfl_xor(s, 1);  s  += __shfl_xor(s, 2);  s  += __shfl_xor(s, 4);
        s  += __shfl_xor(s, 8);  s  += __shfl_xor(s, 16);
        s2 += __shfl_xor(s2, 1); s2 += __shfl_xor(s2, 2); s2 += __shfl_xor(s2, 4);
        s2 += __shfl_xor(s2, 8); s2 += __shfl_xor(s2, 16);
        float mu  = s * (1.f / HID);
        float var = s2 * (1.f / HID) - mu * mu;
        float inv = rsqrtf(var + 1e-5f);
        unsigned short hi4[4], lo4[4];
#pragma unroll
        for (int j = 0; j < 4; ++j) {
            int c = cb + j;
            float o = (v[j] - mu) * inv * g[c] + b[c];
            hi4[j] = f2b(o); lo4[j] = f2b(o - us2f(hi4[j]));
        }
        *(uint2*)&sAh[row * 136 + cb] = *(const uint2*)hi4;
        *(uint2*)&sAl[row * 136 + cb] = *(const uint2*)lo4;
    }
    __syncthreads();

    // ---- GEMM1: hid[16][512]; wave w -> k-cols [w*64, w*64+64). 48 MFMA/wave.
    f32x4 acc1[4];
#pragma unroll
    for (int i = 0; i < 4; ++i) acc1[i] = (f32x4){0.f, 0.f, 0.f, 0.f};
#pragma unroll
    for (int c = 0; c < 4; ++c) {
        bf16x8 ah = *(const bf16x8*)&sAh[m * 136 + c * 32 + quad * 8];
        bf16x8 al = *(const bf16x8*)&sAl[m * 136 + c * 32 + quad * 8];
#pragma unroll
        for (int nt = 0; nt < 4; ++nt) {
            bf16x8 wh = (c == 0) ? p1h[nt] : *(const bf16x8*)&w1h[nt * 16 * 128 + c * 32];
            bf16x8 wl = (c == 0) ? p1l[nt] : *(const bf16x8*)&w1l[nt * 16 * 128 + c * 32];
            acc1[nt] = __builtin_amdgcn_mfma_f32_16x16x32_bf16(wh, ah, acc1[nt], 0, 0, 0);
            acc1[nt] = __builtin_amdgcn_mfma_f32_16x16x32_bf16(wh, al, acc1[nt], 0, 0, 0);
            acc1[nt] = __builtin_amdgcn_mfma_f32_16x16x32_bf16(wl, ah, acc1[nt], 0, 0, 0);
        }
    }
    // relu + split + packed store: 4 consecutive k of row m per nt -> one 8B write per plane
#pragma unroll
    for (int nt = 0; nt < 4; ++nt) {
        unsigned short hi4[4], lo4[4];
#pragma unroll
        for (int r = 0; r < 4; ++r) {
            float v = fmaxf(acc1[nt][r], 0.f);
            hi4[r] = f2b(v);
            lo4[r] = f2b(v - us2f(hi4[r]));
        }
        int kk = w * 64 + nt * 16 + quad * 4;
        *(uint2*)&sHh[m * 520 + kk] = *(const uint2*)hi4;
        *(uint2*)&sHl[m * 520 + kk] = *(const uint2*)lo4;
    }

    // W2 fragment base; prefetch c=0 above the barrier
    const unsigned short* w2h = W2H_ + (long)(w * 16 + m) * 512 + quad * 8;
    const unsigned short* w2l = W2L_ + (long)(w * 16 + m) * 512 + quad * 8;
    bf16x8 p2h = *(const bf16x8*)w2h;
    bf16x8 p2l = *(const bf16x8*)w2l;
    __syncthreads();

    // ---- GEMM2: out[16][128]; wave w -> cols [w*16, w*16+16). 48 MFMA/wave.
    f32x4 acc2 = (f32x4){0.f, 0.f, 0.f, 0.f};
#pragma unroll
    for (int c = 0; c < 16; ++c) {
        bf16x8 ah = *(const bf16x8*)&sHh[m * 520 + c * 32 + quad * 8];
        bf16x8 al = *(const bf16x8*)&sHl[m * 520 + c * 32 + quad * 8];
        bf16x8 wh = (c == 0) ? p2h : *(const bf16x8*)&w2h[c * 32];
        bf16x8 wl = (c == 0) ? p2l : *(const bf16x8*)&w2l[c * 32];
        acc2 = __builtin_amdgcn_mfma_f32_16x16x32_bf16(ah, wh, acc2, 0, 0, 0);
        acc2 = __builtin_amdgcn_mfma_f32_16x16x32_bf16(ah, wl, acc2, 0, 0, 0);
        acc2 = __builtin_amdgcn_mfma_f32_16x16x32_bf16(al, wh, acc2, 0, 0, 0);
    }
    __syncthreads();                    // all sHh/sHl reads done; reuse as fp32 tile
    float* ht = (float*)&sHh[0];        // [16][132]
#pragma unroll
    for (int r = 0; r < 4; ++r) {
        int row = quad * 4 + r;
        int col = w * 16 + m;
        float v = acc2[r] + y[(long)(row0 + row) * HID + col];
        hout[(long)(row0 + row) * HID + col] = v;
        ht[row * 132 + col] = v;
    }
    __syncthreads();
    if (Wdec) {                         // last layer: fused decode out = 10*tanh((h@Wdec)/sqrt(128))
        if (t < 256) {
            int row = t >> 4, sub = t & 15;
            float vv[8];
            *(float4*)&vv[0] = *(const float4*)&ht[row * 132 + sub * 8];
            *(float4*)&vv[4] = *(const float4*)&ht[row * 132 + sub * 8 + 4];
            float a = 0.f;
#pragma unroll
            for (int j = 0; j < 8; ++j) a += vv[j] * Wdec[sub * 8 + j];
            a += __shfl_xor(a, 1); a += __shfl_xor(a, 2); a += __shfl_xor(a, 4); a += __shfl_xor(a, 8);
            if (sub == 0) out[row0 + row] = 10.f * tanhf(a * 0.08838834764831845f);
        }
    } else {                            // non-last: LN1 of next layer from ht -> A planes
        int row = t >> 5, cb = (t & 31) * 4;
        float v[4];
        v[0] = ht[row * 132 + cb];     v[1] = ht[row * 132 + cb + 1];
        v[2] = ht[row * 132 + cb + 2]; v[3] = ht[row * 132 + cb + 3];
        float s = v[0] + v[1] + v[2] + v[3];
        float s2 = v[0]*v[0] + v[1]*v[1] + v[2]*v[2] + v[3]*v[3];
        s  += __shfl_xor(s, 1);  s  += __shfl_xor(s, 2);  s  += __shfl_xor(s, 4);
        s  += __shfl_xor(s, 8);  s  += __shfl_xor(s, 16);
        s2 += __shfl_xor(s2, 1); s2 += __shfl_xor(s2, 2); s2 += __shfl_xor(s2, 4);
        s2 += __shfl_xor(s2, 8); s2 += __shfl_xor(s2, 16);
        float mu  = s * (1.f / HID);
        float var = s2 * (1.f / HID) - mu * mu;
        float inv = rsqrtf(var + 1e-5f);
        unsigned short hi4[4], lo4[4];
#pragma unroll
        for (int j = 0; j < 4; ++j) {
            int c = cb + j;
            float o = (v[j] - mu) * inv * lng[c] + lnb[c];
            hi4[j] = f2b(o); lo4[j] = f2b(o - us2f(hi4[j]));
        }
        *(uint2*)&AHo[(long)(row0 + row) * HID + cb] = *(const uint2*)hi4;
        *(uint2*)&ALo[(long)(row0 + row) * HID + cb] = *(const uint2*)lo4;
    }
}

// ---------- attention: grid 512 = b x head x quarter; 4 waves x 16 q-rows.
// qkv arrives TRANSPOSED [384][4096] -> fully coalesced staging loads; V LDS writes
// vectorized. Softmax in batch form (64 ef loads issued together = max MLP).
#define PAS 268   // u16 stride, 134 dwords === 6 mod 32 -> bank-floor frag reads/stores
#define KQS 20    // u16 stride for K/Q planes, 10 dwords -> bank-floor frag reads
__global__ __launch_bounds__(256) void k_attn(
    const unsigned short* __restrict__ qkvH, const unsigned short* __restrict__ qkvL,
    const float* __restrict__ ef, const float* __restrict__ sbuf,
    int layer, float* __restrict__ y)
{
    __shared__ unsigned short Kh[NS * KQS], Kl[NS * KQS];    // [key][d]
    __shared__ unsigned short Qh[64 * KQS], Ql[64 * KQS];    // [qrow][d]
    __shared__ unsigned short Vh[16 * PAS], Vl[16 * PAS];    // [d][key]
    __shared__ unsigned short Pa[4][16 * PAS];               // per-wave [qrow][key]
    int bid = blockIdx.x;
    int q4 = bid & 3, hh = (bid >> 2) & 7, bb = bid >> 5;
    int t = threadIdx.x;
    {   // K,V staging from qkvT: thread (d = t>>4, keychunk = (t&15)*16): coalesced 32B runs
        int d = t >> 4, kc = (t & 15) * 16;
        long base = (long)ROWS * (HID + hh * 16 + d) + bb * NS + kc;
        long vbase = base + (long)ROWS * 128;
        union { uint4 u[2]; unsigned short s[16]; } KH, KL, VH, VL;
        KH.u[0] = *(const uint4*)&qkvH[base];      KH.u[1] = *(const uint4*)&qkvH[base + 8];
        KL.u[0] = *(const uint4*)&qkvL[base];      KL.u[1] = *(const uint4*)&qkvL[base + 8];
        VH.u[0] = *(const uint4*)&qkvH[vbase];     VH.u[1] = *(const uint4*)&qkvH[vbase + 8];
        VL.u[0] = *(const uint4*)&qkvL[vbase];     VL.u[1] = *(const uint4*)&qkvL[vbase + 8];
#pragma unroll
        for (int j = 0; j < 16; ++j) {             // K -> [key][d] (scatter)
            Kh[(kc + j) * KQS + d] = KH.s[j];
            Kl[(kc + j) * KQS + d] = KL.s[j];
        }
#pragma unroll
        for (int j = 0; j < 4; ++j) {              // V -> [d][key] (contiguous, vectorized)
            *(uint2*)&Vh[d * PAS + kc + j * 4] = *(const uint2*)&VH.s[j * 4];
            *(uint2*)&Vl[d * PAS + kc + j * 4] = *(const uint2*)&VL.s[j * 4];
        }
    }
    {   // Q staging from qkvT: thread (d = t>>4, rowchunk = (t&15)*4): coalesced 8B runs
        int d = t >> 4, rc = (t & 15) * 4;
        long qb = (long)ROWS * (hh * 16 + d) + bb * NS + q4 * 64 + rc;
        union { uint2 u; unsigned short s[4]; } QH, QL;
        QH.u = *(const uint2*)&qkvH[qb];
        QL.u = *(const uint2*)&qkvL[qb];
#pragma unroll
        for (int j = 0; j < 4; ++j) {
            Qh[(rc + j) * KQS + d] = QH.s[j];
            Ql[(rc + j) * KQS + d] = QL.s[j];
        }
    }
    __syncthreads();
    int w = t >> 6, lane = t & 63;
    int m = lane & 15, quad = lane >> 4;
    float s1  = sbuf[layer * 16 + hh];
    float s2g = sbuf[layer * 16 + NHEAD + hh];
    unsigned short* Paw = Pa[w];

    // Q A-fragment (once per wave): quads 2,3 = zero pad (k 16..31)
    bf16x8 qh = (bf16x8){0,0,0,0,0,0,0,0}, ql = qh;
    if (quad < 2) {
        qh = *(const bf16x8*)&Qh[(w * 16 + m) * KQS + quad * 8];
        ql = *(const bf16x8*)&Ql[(w * 16 + m) * KQS + quad * 8];
    }
    // QK^T via MFMA: 16 col-tiles of 16 keys
    f32x4 sc[16];
#pragma unroll
    for (int ct = 0; ct < 16; ++ct) {
        bf16x8 kh = (bf16x8){0,0,0,0,0,0,0,0}, kl = kh;
        if (quad < 2) {
            kh = *(const bf16x8*)&Kh[(ct * 16 + m) * KQS + quad * 8];
            kl = *(const bf16x8*)&Kl[(ct * 16 + m) * KQS + quad * 8];
        }
        f32x4 a = (f32x4){0.f, 0.f, 0.f, 0.f};
        a = __builtin_amdgcn_mfma_f32_16x16x32_bf16(qh, kh, a, 0, 0, 0);
        a = __builtin_amdgcn_mfma_f32_16x16x32_bf16(qh, kl, a, 0, 0, 0);
        a = __builtin_amdgcn_mfma_f32_16x16x32_bf16(ql, kh, a, 0, 0, 0);
        sc[ct] = a;
    }
    // softmax, deferred normalization: Pa = p*e, running row-sums only (batched ef loads).
    int baserow = q4 * 64 + w * 16 + quad * 4;
    float s[4] = {0.f, 0.f, 0.f, 0.f};
#pragma unroll
    for (int ct = 0; ct < 16; ++ct) {
#pragma unroll
        for (int r = 0; r < 4; ++r) {
            float e = ef[((long)(bb * NS + baserow + r)) * NS + ct * 16 + m];
            float p = __expf(sc[ct][r] * 0.25f + e * s1);
            s[r] += p;
            Paw[(quad * 4 + r) * PAS + ct * 16 + m] = f2b(p * e);
        }
    }
    float inv[4];
#pragma unroll
    for (int r = 0; r < 4; ++r) {
        float ss = s[r];
        ss += __shfl_xor(ss, 1); ss += __shfl_xor(ss, 2);
        ss += __shfl_xor(ss, 4); ss += __shfl_xor(ss, 8);
        inv[r] = s2g / ss;
    }
    // no barrier: Pa is wave-private (same-wave LDS ops are in-order);
    // V/K were covered by the staging barrier above.
    f32x4 acc = (f32x4){0.f, 0.f, 0.f, 0.f};
#pragma unroll
    for (int sft = 0; sft < 8; ++sft) {
        bf16x8 pf = *(const bf16x8*)&Paw[m * PAS + sft * 32 + quad * 8];
        bf16x8 vh = *(const bf16x8*)&Vh[m * PAS + sft * 32 + quad * 8];
        bf16x8 vl = *(const bf16x8*)&Vl[m * PAS + sft * 32 + quad * 8];
        acc = __builtin_amdgcn_mfma_f32_16x16x32_bf16(pf, vh, acc, 0, 0, 0);
        acc = __builtin_amdgcn_mfma_f32_16x16x32_bf16(pf, vl, acc, 0, 0, 0);
    }
#pragma unroll
    for (int r = 0; r < 4; ++r) {
        int row = q4 * 64 + w * 16 + quad * 4 + r;
        y[((long)(bb * NS + row)) * HID + hh * 16 + m] = acc[r] * inv[r];
    }
}

extern "C" void kernel_launch(void* const* d_in, const int* in_sizes, int n_in,
                              void* d_out, int out_size, void* d_ws, size_t ws_size,
                              hipStream_t stream) {
    const float* nf    = (const float*)d_in[0];
    const float* ef    = (const float*)d_in[1];
    const float* Wn    = (const float*)d_in[2];
    const float* We_in = (const float*)d_in[3];
    const float* ln1g  = (const float*)d_in[4];
    const float* ln1b  = (const float*)d_in[5];
    const float* Wh    = (const float*)d_in[6];
    const float* We    = (const float*)d_in[7];
    const float* ln2g  = (const float*)d_in[8];
    const float* ln2b  = (const float*)d_in[9];
    const float* W1    = (const float*)d_in[10];
    const float* W2    = (const float*)d_in[11];
    const float* Wdec  = (const float*)d_in[12];

    float* ws   = (float*)d_ws;
    float* sbuf = ws;                            // 64 slots
    float* h    = ws + 64;                       // 4096*128
    float* y    = h + ROWS * HID;                // 4096*128
    unsigned short* qkvH = (unsigned short*)(y + ROWS * HID);   // TRANSPOSED [384][4096] u16
    unsigned short* qkvL = qkvH + (long)384 * ROWS;
    unsigned short* WhH  = qkvL + (long)384 * ROWS;             // 3*384*128
    unsigned short* WhL  = WhH + (long)NL * 384 * 128;
    unsigned short* W1H  = WhL + (long)NL * 384 * 128;          // 3*512*128
    unsigned short* W1L  = W1H + (long)NL * 512 * 128;
    unsigned short* W2H  = W1L + (long)NL * 512 * 128;          // 3*128*512
    unsigned short* W2L  = W2H + (long)NL * 128 * 512;
    unsigned short* AH   = W2L + (long)NL * 128 * 512;          // pre-LN'd A planes [4096][128]
    unsigned short* AL   = AH + (long)ROWS * HID;

    k_prep<<<529 + ROWS * HID / 1024, 256, 0, stream>>>(Wh, W1, W2, We_in, We, nf, Wn,
                                    ln1g, ln1b,
                                    WhH, WhL, W1H, W1L, W2H, W2L, AH, AL, sbuf, h);
    for (int l = 0; l < NL; ++l) {
        // QKV GEMM on pre-LN'd planes -> transposed split planes
        k_fgemm<<<dim3(6, 64), 256, 0, stream>>>(AH, AL,
            WhH + (long)l * 384 * 128, WhL + (long)l * 384 * 128,
            qkvH, qkvL);
        k_attn<<<512, 256, 0, stream>>>(qkvH, qkvL, ef, sbuf, l, y);
        // fused LN2 + W1 + relu + W2 + residual + (LN1 of next layer | decode)
        int last = (l == NL - 1);
        k_mlp<<<ROWS / 16, 512, 0, stream>>>(y, h,
            ln2g + l * HID, ln2b + l * HID,
            ln1g + (last ? 0 : (l + 1) * HID), ln1b + (last ? 0 : (l + 1) * HID),
            W1H + (long)l * 512 * 128, W1L + (long)l * 512 * 128,
            W2H + (long)l * 128 * 512, W2L + (long)l * 128 * 512,
            h, AH, AL, last ? Wdec : nullptr, (float*)d_out);
    }
}